// Round 3
// baseline (541.768 us; speedup 1.0000x reference)
//
#include <hip/hip_runtime.h>
#include <hip/hip_bf16.h>

typedef unsigned short u16;
typedef unsigned int u32;

typedef short bf16x8 __attribute__((ext_vector_type(8)));
typedef float f32x4 __attribute__((ext_vector_type(4)));

__device__ __forceinline__ u16 f2bf(float f) {
    union { float f; u32 u; } v; v.f = f;
    u32 u = v.u;
    u32 r = (u + 0x7fffu + ((u >> 16) & 1u)) >> 16;
    return (u16)r;
}
__device__ __forceinline__ float bf2f(u16 b) {
    union { u32 u; float f; } v; v.u = ((u32)b) << 16;
    return v.f;
}

// ---------------------------------------------------------------------------
// Generic 128x128-tile bf16 MFMA GEMM: C = scale * (A @ B) [+ bias] [relu]
//   A: [M,K] row-major (fp32 -> converted, or bf16)
//   B: either [K,N] row-major (transpose-staged into LDS as [n][k])
//      or (B_NK) [N,K] row-major bf16 (A-style staging; computes A @ B^T)
//   C: [M,N], fp32 or bf16
// 4 waves (2x2), each wave 64x64 via 4x4 frags of 16x16x32 MFMA.
// ---------------------------------------------------------------------------
template<bool A_F32, bool B_F32, bool B_NK, bool OUT_F32, bool RELU, bool HAS_BIAS>
__global__ __launch_bounds__(256) void gemm_k(
    const void* __restrict__ Ap, const void* __restrict__ Bp, void* __restrict__ Cp,
    const float* __restrict__ bias, float scale,
    int K, int lda, int ldb, int ldc,
    long strideA, long strideB, long strideC)
{
    __shared__ u16 As[128][40];   // +8 pad: keeps ds_read_b128 16B-aligned, ~2-way banks
    __shared__ u16 Bs[128][40];

    const int tid  = threadIdx.x;
    const int lane = tid & 63;
    const int wave = tid >> 6;
    const int wm = (wave >> 1) * 64, wn = (wave & 1) * 64;
    const int row0 = blockIdx.x * 128;
    const int col0 = blockIdx.y * 128;
    const long batch = blockIdx.z;

    const float* Af = (const float*)Ap + batch * strideA;
    const u16*   Ab = (const u16*)Ap + batch * strideA;
    const float* Bf = (const float*)Bp + batch * strideB;
    const u16*   Bb = (const u16*)Bp + batch * strideB;

    f32x4 acc[4][4] = {};

    for (int k0 = 0; k0 < K; k0 += 32) {
        // ---- stage A tile [128 rows][32 k] ----
        if constexpr (A_F32) {
            // 128 rows x 8 float4-chunks = 1024 chunk-writes
            #pragma unroll
            for (int i = 0; i < 4; ++i) {
                int idx = tid + i * 256;
                int r = idx >> 3, q = idx & 7;
                const float4 v = *(const float4*)(Af + (size_t)(row0 + r) * lda + k0 + q * 4);
                ushort4 o;
                o.x = f2bf(v.x); o.y = f2bf(v.y); o.z = f2bf(v.z); o.w = f2bf(v.w);
                *(ushort4*)&As[r][q * 4] = o;
            }
        } else {
            // 128 rows x 4 int4-chunks (32 bf16/row) = 512 chunk-writes
            #pragma unroll
            for (int i = 0; i < 2; ++i) {
                int idx = tid + i * 256;
                int r = idx >> 2, h = idx & 3;   // FIXED: was >>1 / &1 (LDS overflow + unwritten k16..31)
                *(int4*)&As[r][h * 8] = *(const int4*)(Ab + (size_t)(row0 + r) * lda + k0 + h * 8);
            }
        }
        // ---- stage B tile as Bs[n][k] ----
        if constexpr (B_NK) {
            // B given as [N][K] bf16 (i.e. computing A @ B^T): same staging as A
            #pragma unroll
            for (int i = 0; i < 2; ++i) {
                int idx = tid + i * 256;
                int r = idx >> 2, h = idx & 3;   // FIXED (same as A path)
                *(int4*)&Bs[r][h * 8] = *(const int4*)(Bb + (size_t)(col0 + r) * ldb + k0 + h * 8);
            }
        } else if constexpr (B_F32) {
            // [32 k][128 n] fp32: 32k x 32 float4-chunks = 1024
            #pragma unroll
            for (int i = 0; i < 4; ++i) {
                int idx = tid + i * 256;
                int k = idx >> 5, nq = idx & 31;
                const float4 v = *(const float4*)(Bf + (size_t)(k0 + k) * ldb + col0 + nq * 4);
                Bs[nq * 4 + 0][k] = f2bf(v.x);
                Bs[nq * 4 + 1][k] = f2bf(v.y);
                Bs[nq * 4 + 2][k] = f2bf(v.z);
                Bs[nq * 4 + 3][k] = f2bf(v.w);
            }
        } else {
            // [32 k][128 n] bf16: 32k x 16 int4-chunks = 512
            #pragma unroll
            for (int i = 0; i < 2; ++i) {
                int idx = tid + i * 256;
                int k = idx >> 4, n8 = idx & 15;
                int4 v = *(const int4*)(Bb + (size_t)(k0 + k) * ldb + col0 + n8 * 8);
                const u16* pv = (const u16*)&v;
                #pragma unroll
                for (int j = 0; j < 8; ++j) Bs[n8 * 8 + j][k] = pv[j];
            }
        }
        __syncthreads();

        bf16x8 a[4], b[4];
        #pragma unroll
        for (int m = 0; m < 4; ++m)
            a[m] = *(const bf16x8*)&As[wm + m * 16 + (lane & 15)][(lane >> 4) * 8];
        #pragma unroll
        for (int n = 0; n < 4; ++n)
            b[n] = *(const bf16x8*)&Bs[wn + n * 16 + (lane & 15)][(lane >> 4) * 8];
        #pragma unroll
        for (int m = 0; m < 4; ++m)
            #pragma unroll
            for (int n = 0; n < 4; ++n)
                acc[m][n] = __builtin_amdgcn_mfma_f32_16x16x32_bf16(a[m], b[n], acc[m][n], 0, 0, 0);
        __syncthreads();
    }

    // ---- epilogue: C/D frag layout col=lane&15, row=(lane>>4)*4+reg (m89) ----
    float* Cf = (float*)Cp + batch * strideC;
    u16*   Cb = (u16*)Cp + batch * strideC;
    #pragma unroll
    for (int m = 0; m < 4; ++m) {
        #pragma unroll
        for (int n = 0; n < 4; ++n) {
            #pragma unroll
            for (int r = 0; r < 4; ++r) {
                int row = row0 + wm + m * 16 + (lane >> 4) * 4 + r;
                int col = col0 + wn + n * 16 + (lane & 15);
                float v = acc[m][n][r] * scale;
                if constexpr (HAS_BIAS) v += bias[col];
                if constexpr (RELU) v = fmaxf(v, 0.f);
                if constexpr (OUT_F32) Cf[(size_t)row * ldc + col] = v;
                else                   Cb[(size_t)row * ldc + col] = f2bf(v);
            }
        }
    }
}

// ---------------------------------------------------------------------------
// Row softmax over S[32768][256] (fp32) -> attn (bf16), attnw = attn+pos (bf16)
// One wave per row, 4 cols/lane.
// ---------------------------------------------------------------------------
__global__ __launch_bounds__(256) void softmax1_k(
    const float* __restrict__ S, u16* __restrict__ attn, u16* __restrict__ attnw,
    const float* __restrict__ pos)
{
    const int lane = threadIdx.x & 63;
    const int row  = blockIdx.x * 4 + (threadIdx.x >> 6);
    const float* s = S + (size_t)row * 256;
    float v[4];
    #pragma unroll
    for (int i = 0; i < 4; ++i) v[i] = s[lane + i * 64];
    float mx = fmaxf(fmaxf(v[0], v[1]), fmaxf(v[2], v[3]));
    #pragma unroll
    for (int o = 32; o; o >>= 1) mx = fmaxf(mx, __shfl_xor(mx, o, 64));
    float e[4], sum = 0.f;
    #pragma unroll
    for (int i = 0; i < 4; ++i) { e[i] = __expf(v[i] - mx); sum += e[i]; }
    #pragma unroll
    for (int o = 32; o; o >>= 1) sum += __shfl_xor(sum, o, 64);
    const float inv = 1.f / sum;
    const int c = (row >> 8) & 15, r = row & 255;
    const float* p = pos + ((size_t)(c * 256 + r)) * 256;
    #pragma unroll
    for (int i = 0; i < 4; ++i) {
        int col = lane + i * 64;
        float a = e[i] * inv;
        attn [(size_t)row * 256 + col] = f2bf(a);
        attnw[(size_t)row * 256 + col] = f2bf(a + p[col]);
    }
}

// ---------------------------------------------------------------------------
// wrow[row] = h[row,:] . w2 + b2   (h bf16 [32768][256])
// ---------------------------------------------------------------------------
__global__ __launch_bounds__(256) void wrow_k(
    const u16* __restrict__ h, const float* __restrict__ w2,
    const float* __restrict__ b2, float* __restrict__ wrow)
{
    const int lane = threadIdx.x & 63;
    const int row  = blockIdx.x * 4 + (threadIdx.x >> 6);
    const u16* hr = h + (size_t)row * 256;
    float acc = 0.f;
    #pragma unroll
    for (int i = 0; i < 4; ++i) { int col = lane + i * 64; acc += bf2f(hr[col]) * w2[col]; }
    #pragma unroll
    for (int o = 32; o; o >>= 1) acc += __shfl_xor(acc, o, 64);
    if (lane == 0) wrow[row] = acc + b2[0];
}

// ---------------------------------------------------------------------------
// attn2 = softmax_row( attn * exp(-(col-r)^2 / (2 w^2 + 1e-6)) )  -> bf16
// ---------------------------------------------------------------------------
__global__ __launch_bounds__(256) void attn2_k(
    const u16* __restrict__ attn, const float* __restrict__ wrow, u16* __restrict__ attn2)
{
    const int lane = threadIdx.x & 63;
    const int row  = blockIdx.x * 4 + (threadIdx.x >> 6);
    const int r = row & 255;
    const float w = wrow[row];
    const float inv_den = 1.f / (2.f * w * w + 1e-6f);
    float v[4];
    #pragma unroll
    for (int i = 0; i < 4; ++i) {
        int col = lane + i * 64;
        float d = (float)(col - r);
        v[i] = bf2f(attn[(size_t)row * 256 + col]) * __expf(-(d * d) * inv_den);
    }
    float mx = fmaxf(fmaxf(v[0], v[1]), fmaxf(v[2], v[3]));
    #pragma unroll
    for (int o = 32; o; o >>= 1) mx = fmaxf(mx, __shfl_xor(mx, o, 64));
    float e[4], sum = 0.f;
    #pragma unroll
    for (int i = 0; i < 4; ++i) { e[i] = __expf(v[i] - mx); sum += e[i]; }
    #pragma unroll
    for (int o = 32; o; o >>= 1) sum += __shfl_xor(sum, o, 64);
    const float inv = 1.f / sum;
    #pragma unroll
    for (int i = 0; i < 4; ++i)
        attn2[(size_t)row * 256 + lane + i * 64] = f2bf(e[i] * inv);
}

// ---------------------------------------------------------------------------
extern "C" void kernel_launch(void* const* d_in, const int* in_sizes, int n_in,
                              void* d_out, int out_size, void* d_ws, size_t ws_size,
                              hipStream_t stream) {
    const float* x     = (const float*)d_in[0];   // [8,16,256,512]
    const float* w_qkv = (const float*)d_in[1];   // [512,1536]
    const float* pos   = (const float*)d_in[2];   // [1,16,256,256]
    const float* w1    = (const float*)d_in[3];   // [256,256]
    const float* b1    = (const float*)d_in[4];   // [256]
    const float* w2    = (const float*)d_in[5];   // [256]
    const float* b2    = (const float*)d_in[6];   // [1]
    const float* w_out = (const float*)d_in[7];   // [512,512]
    const float* b_out = (const float*)d_in[8];   // [512]
    float* out = (float*)d_out;                   // fp32 output (ref returns fp32)
    char* ws = (char*)d_ws;

    // workspace layout (bytes); S-region and attn-region reused later
    u16*   qkv   = (u16*)(ws);                    // [32768][1536] bf16  96 MB
    float* S     = (float*)(ws + 100663296);      // [128][256][256] f32 32 MB
    u16*   attn  = (u16*)(ws + 134217728);        // 16 MB
    u16*   attnw = (u16*)(ws + 150994944);        // 16 MB
    u16*   hbuf  = (u16*)(ws + 167772160);        // 16 MB
    float* wrow  = (float*)(ws + 184549376);      // 128 KB
    u16*   attn2 = (u16*)(ws + 100663296);        // reuse S       16 MB
    u16*   av    = (u16*)(ws + 134217728);        // reuse attn+attnw 32 MB

    if (ws_size < (size_t)184680448) return;  // insufficient scratch -> clean fail

    dim3 blk(256);
    const long LBC = 256L * 1536L;

    // 1. qkv = x @ w_qkv                  [32768,512]x[512,1536] -> bf16
    gemm_k<true, true, false, false, false, false><<<dim3(256, 12, 1), blk, 0, stream>>>(
        x, w_qkv, qkv, nullptr, 1.f, 512, 512, 1536, 1536, 0, 0, 0);

    // 2. S = 0.125 * q @ k^T  (per b,c)   [256,512]x[512,256]^T -> f32
    gemm_k<false, false, true, true, false, false><<<dim3(2, 2, 128), blk, 0, stream>>>(
        qkv, qkv + 512, S, nullptr, 0.125f, 512, 1536, 1536, 256, LBC, LBC, 65536L);

    // 3. attn = softmax(S); attnw = attn + pos
    softmax1_k<<<dim3(8192), blk, 0, stream>>>(S, attn, attnw, pos);

    // 4. h = relu(attnw @ w1 + b1)        per (b,c) [256,256]x[256,256] -> bf16
    gemm_k<false, true, false, false, true, true><<<dim3(2, 2, 128), blk, 0, stream>>>(
        attnw, w1, hbuf, b1, 1.f, 256, 256, 256, 256, 65536L, 0L, 65536L);

    // 5. wrow = h @ w2 + b2
    wrow_k<<<dim3(8192), blk, 0, stream>>>(hbuf, w2, b2, wrow);

    // 6. attn2 = softmax(attn * gaussian-decay)
    attn2_k<<<dim3(8192), blk, 0, stream>>>(attn, wrow, attn2);

    // 7. av = attn2 @ v                   per (b,c) [256,256]x[256,512] -> bf16
    gemm_k<false, false, false, false, false, false><<<dim3(2, 4, 128), blk, 0, stream>>>(
        attn2, qkv + 1024, av, nullptr, 1.f, 256, 256, 1536, 512, 65536L, LBC, 131072L);

    // 8. out = av @ w_out + b_out         [32768,512]x[512,512] -> f32 out
    gemm_k<false, true, false, true, false, true><<<dim3(256, 4, 1), blk, 0, stream>>>(
        av, w_out, out, b_out, 1.f, 512, 512, 512, 512, 0, 0, 0);
}

// Round 4
// 380.905 us; speedup vs baseline: 1.4223x; 1.4223x over previous
//
#include <hip/hip_runtime.h>
#include <hip/hip_bf16.h>

typedef unsigned short u16;
typedef unsigned int u32;

typedef short bf16x8 __attribute__((ext_vector_type(8)));
typedef float f32x4 __attribute__((ext_vector_type(4)));

__device__ __forceinline__ u16 f2bf(float f) {
    union { float f; u32 u; } v; v.f = f;
    u32 u = v.u;
    return (u16)((u + 0x7fffu + ((u >> 16) & 1u)) >> 16);
}
__device__ __forceinline__ float bf2f(u16 b) {
    union { u32 u; float f; } v; v.u = ((u32)b) << 16;
    return v.f;
}

// async global->LDS 16B: lane l of the wave lands at uniform_base + l*16B.
__device__ __forceinline__ void gload16(const u16* g, u16* lds_uniform_base, int lane) {
#if __has_builtin(__builtin_amdgcn_global_load_lds)
    __builtin_amdgcn_global_load_lds((const __attribute__((address_space(1))) void*)g,
                                     (__attribute__((address_space(3))) void*)lds_uniform_base,
                                     16, 0, 0);
#else
    *(int4*)(lds_uniform_base + lane * 8) = *(const int4*)g;
#endif
}

// ---------------------------------------------------------------------------
// bf16 MFMA GEMM, 128x128 tile, BK=32, 4 waves (2x2), 4x4 frags 16x16x32.
//   C = scale*(A @ B^T) [+bias] [relu];  A:[M,K] bf16, B:[N,K] bf16.
//   AMODE 0: A staged via global_load_lds. AMODE 1: A = bf16(attn) + fp32 pos
//            (fused add, manual swizzled ds_write), pos row = batch&15.
// LDS layout: [128 rows][4 slots of 16B], slot XOR-swizzled:
//   stored_slot = natural_slot ^ (row&3) ^ ((row>>2)&3)   (involution)
// ---------------------------------------------------------------------------
template<int AMODE, bool OUT_F32, bool RELU, bool HAS_BIAS>
__global__ __launch_bounds__(256) void gemm2_k(
    const u16* __restrict__ A, const u16* __restrict__ B, void* __restrict__ Cp,
    const float* __restrict__ bias, const float* __restrict__ pos, float scale,
    int K, int lda, int ldb, int ldc, long sA, long sB, long sC)
{
    __shared__ u16 As[128 * 32];
    __shared__ u16 Bs[128 * 32];

    const int tid   = threadIdx.x;
    const int lane  = tid & 63;
    const int wave  = tid >> 6;
    const int wbase = tid & ~63;               // wave-uniform chunk base
    const int wm = (wave >> 1) * 64, wn = (wave & 1) * 64;
    const int row0 = blockIdx.x * 128;
    const int col0 = blockIdx.y * 128;
    const long batch = blockIdx.z;

    const u16* Ab = A + batch * sA;
    const u16* Bb = B + batch * sB;
    const float* posb = (AMODE == 1) ? pos + (size_t)(batch & 15) * 65536 : nullptr;

    // per-lane swizzled read slot (constant across m/n frags; see swizzle note)
    const int slotp = (lane >> 4) ^ (lane & 3) ^ ((lane >> 2) & 3);

    f32x4 acc[4][4] = {};

    for (int k0 = 0; k0 < K; k0 += 32) {
        if constexpr (AMODE == 0) {
            #pragma unroll
            for (int i = 0; i < 2; ++i) {
                int idx = tid + i * 256;                    // lane-contig within wave
                int r = idx >> 2, c = idx & 3;
                int s = c ^ (r & 3) ^ ((r >> 2) & 3);       // inverse-swizzled source slot
                gload16(Ab + (size_t)(row0 + r) * lda + k0 + s * 8,
                        &As[(size_t)(wbase + i * 256) * 8], lane);
            }
        } else {
            #pragma unroll
            for (int i = 0; i < 2; ++i) {
                int idx = tid + i * 256;
                int r = idx >> 2, c = idx & 3;
                int gr = row0 + r;
                const u16*  ap = Ab + (size_t)gr * lda + k0 + c * 8;
                const float* pp = posb + (size_t)gr * 256 + k0 + c * 8;
                int4 av4 = *(const int4*)ap;
                float4 p0 = *(const float4*)pp, p1 = *(const float4*)(pp + 4);
                const u16* ae = (const u16*)&av4;
                u16 o[8];
                o[0] = f2bf(bf2f(ae[0]) + p0.x); o[1] = f2bf(bf2f(ae[1]) + p0.y);
                o[2] = f2bf(bf2f(ae[2]) + p0.z); o[3] = f2bf(bf2f(ae[3]) + p0.w);
                o[4] = f2bf(bf2f(ae[4]) + p1.x); o[5] = f2bf(bf2f(ae[5]) + p1.y);
                o[6] = f2bf(bf2f(ae[6]) + p1.z); o[7] = f2bf(bf2f(ae[7]) + p1.w);
                int sl = c ^ (r & 3) ^ ((r >> 2) & 3);
                *(int4*)&As[(size_t)r * 32 + sl * 8] = *(const int4*)o;
            }
        }
        #pragma unroll
        for (int i = 0; i < 2; ++i) {
            int idx = tid + i * 256;
            int r = idx >> 2, c = idx & 3;
            int s = c ^ (r & 3) ^ ((r >> 2) & 3);
            gload16(Bb + (size_t)(col0 + r) * ldb + k0 + s * 8,
                    &Bs[(size_t)(wbase + i * 256) * 8], lane);
        }
        __syncthreads();   // emits vmcnt(0)+lgkmcnt(0) drain

        bf16x8 a[4], b[4];
        #pragma unroll
        for (int m = 0; m < 4; ++m)
            a[m] = *(const bf16x8*)&As[(size_t)(wm + m * 16 + (lane & 15)) * 32 + slotp * 8];
        #pragma unroll
        for (int n = 0; n < 4; ++n)
            b[n] = *(const bf16x8*)&Bs[(size_t)(wn + n * 16 + (lane & 15)) * 32 + slotp * 8];
        #pragma unroll
        for (int m = 0; m < 4; ++m)
            #pragma unroll
            for (int n = 0; n < 4; ++n)
                acc[m][n] = __builtin_amdgcn_mfma_f32_16x16x32_bf16(a[m], b[n], acc[m][n], 0, 0, 0);
        __syncthreads();
    }

    // epilogue: C/D frag layout col=lane&15, row=(lane>>4)*4+reg (m89-verified)
    float* Cf = (float*)Cp + batch * sC;
    u16*   Cb = (u16*)Cp + batch * sC;
    #pragma unroll
    for (int m = 0; m < 4; ++m) {
        #pragma unroll
        for (int n = 0; n < 4; ++n) {
            #pragma unroll
            for (int r = 0; r < 4; ++r) {
                int row = row0 + wm + m * 16 + (lane >> 4) * 4 + r;
                int col = col0 + wn + n * 16 + (lane & 15);
                float v = acc[m][n][r] * scale;
                if constexpr (HAS_BIAS) v += bias[col];
                if constexpr (RELU) v = fmaxf(v, 0.f);
                if constexpr (OUT_F32) Cf[(size_t)row * ldc + col] = v;
                else                   Cb[(size_t)row * ldc + col] = f2bf(v);
            }
        }
    }
}

// ---------------------------------------------------------------------------
// fp32 [R][C] -> bf16 [C][R]  (weight transpose+convert), 64x64 tiles
// ---------------------------------------------------------------------------
__global__ __launch_bounds__(256) void trans_f2b_k(
    const float* __restrict__ in, u16* __restrict__ out, int R, int C)
{
    __shared__ u16 t[64][80];
    const int bx = blockIdx.x, by = blockIdx.y;   // bx over C/64, by over R/64
    const int tid = threadIdx.x;
    const int r = tid >> 2, c16 = (tid & 3) * 16;
    const float* ip = in + (size_t)(by * 64 + r) * C + bx * 64 + c16;
    #pragma unroll
    for (int j = 0; j < 4; ++j) {
        float4 v = *(const float4*)(ip + j * 4);
        t[r][c16 + j * 4 + 0] = f2bf(v.x);
        t[r][c16 + j * 4 + 1] = f2bf(v.y);
        t[r][c16 + j * 4 + 2] = f2bf(v.z);
        t[r][c16 + j * 4 + 3] = f2bf(v.w);
    }
    __syncthreads();
    const int orow = tid >> 2, oc = (tid & 3) * 16;
    u16 o[16];
    #pragma unroll
    for (int j = 0; j < 16; ++j) o[j] = t[oc + j][orow];
    u16* op = out + (size_t)(bx * 64 + orow) * R + by * 64 + oc;
    *(int4*)op       = *(const int4*)&o[0];
    *(int4*)(op + 8) = *(const int4*)&o[8];
}

// ---------------------------------------------------------------------------
// bf16 [R][C] (ld=ldin) -> bf16 [C][R], batched (for v -> vT per (b,c))
// ---------------------------------------------------------------------------
__global__ __launch_bounds__(256) void trans_b2b_k(
    const u16* __restrict__ in, u16* __restrict__ out,
    int ldin, int R, long sIn, long sOut)
{
    __shared__ u16 t[64][80];
    const int bx = blockIdx.x, by = blockIdx.y;
    const long z = blockIdx.z;
    const u16* ip = in + z * sIn;
    u16* op = out + z * sOut;
    const int tid = threadIdx.x;
    const int r = tid >> 2, c16 = (tid & 3) * 16;
    const u16* src = ip + (size_t)(by * 64 + r) * ldin + bx * 64 + c16;
    *(int4*)&t[r][c16]     = *(const int4*)src;
    *(int4*)&t[r][c16 + 8] = *(const int4*)(src + 8);
    __syncthreads();
    const int orow = tid >> 2, oc = (tid & 3) * 16;
    u16 o[16];
    #pragma unroll
    for (int j = 0; j < 16; ++j) o[j] = t[oc + j][orow];
    u16* dst = op + (size_t)(bx * 64 + orow) * R + by * 64 + oc;
    *(int4*)dst       = *(const int4*)&o[0];
    *(int4*)(dst + 8) = *(const int4*)&o[8];
}

// fp32 -> bf16 flat convert, 8 elems/thread
__global__ __launch_bounds__(256) void conv_b_k(
    const float* __restrict__ in, u16* __restrict__ out, int n8)
{
    int i = blockIdx.x * 256 + threadIdx.x;
    if (i >= n8) return;
    float4 a = ((const float4*)in)[i * 2], b = ((const float4*)in)[i * 2 + 1];
    u16 o[8] = { f2bf(a.x), f2bf(a.y), f2bf(a.z), f2bf(a.w),
                 f2bf(b.x), f2bf(b.y), f2bf(b.z), f2bf(b.w) };
    ((int4*)out)[i] = *(const int4*)o;
}

// row softmax over S[32768][256] fp32 -> attn bf16 (one wave per row)
__global__ __launch_bounds__(256) void softmax1_k(
    const float* __restrict__ S, u16* __restrict__ attn)
{
    const int lane = threadIdx.x & 63;
    const int row  = blockIdx.x * 4 + (threadIdx.x >> 6);
    const float* s = S + (size_t)row * 256;
    float v[4];
    #pragma unroll
    for (int i = 0; i < 4; ++i) v[i] = s[lane + i * 64];
    float mx = fmaxf(fmaxf(v[0], v[1]), fmaxf(v[2], v[3]));
    #pragma unroll
    for (int o = 32; o; o >>= 1) mx = fmaxf(mx, __shfl_xor(mx, o, 64));
    float e[4], sum = 0.f;
    #pragma unroll
    for (int i = 0; i < 4; ++i) { e[i] = __expf(v[i] - mx); sum += e[i]; }
    #pragma unroll
    for (int o = 32; o; o >>= 1) sum += __shfl_xor(sum, o, 64);
    const float inv = 1.f / sum;
    #pragma unroll
    for (int i = 0; i < 4; ++i)
        attn[(size_t)row * 256 + lane + i * 64] = f2bf(e[i] * inv);
}

// wrow[row] = h[row,:] . w2 + b2
__global__ __launch_bounds__(256) void wrow_k(
    const u16* __restrict__ h, const float* __restrict__ w2,
    const float* __restrict__ b2, float* __restrict__ wrow)
{
    const int lane = threadIdx.x & 63;
    const int row  = blockIdx.x * 4 + (threadIdx.x >> 6);
    const u16* hr = h + (size_t)row * 256;
    float acc = 0.f;
    #pragma unroll
    for (int i = 0; i < 4; ++i) { int col = lane + i * 64; acc += bf2f(hr[col]) * w2[col]; }
    #pragma unroll
    for (int o = 32; o; o >>= 1) acc += __shfl_xor(acc, o, 64);
    if (lane == 0) wrow[row] = acc + b2[0];
}

// attn2 = softmax_row( attn * exp(-(col-r)^2 / (2 w^2 + 1e-6)) )
__global__ __launch_bounds__(256) void attn2_k(
    const u16* __restrict__ attn, const float* __restrict__ wrow, u16* __restrict__ attn2)
{
    const int lane = threadIdx.x & 63;
    const int row  = blockIdx.x * 4 + (threadIdx.x >> 6);
    const int r = row & 255;
    const float w = wrow[row];
    const float inv_den = 1.f / (2.f * w * w + 1e-6f);
    float v[4];
    #pragma unroll
    for (int i = 0; i < 4; ++i) {
        int col = lane + i * 64;
        float d = (float)(col - r);
        v[i] = bf2f(attn[(size_t)row * 256 + col]) * __expf(-(d * d) * inv_den);
    }
    float mx = fmaxf(fmaxf(v[0], v[1]), fmaxf(v[2], v[3]));
    #pragma unroll
    for (int o = 32; o; o >>= 1) mx = fmaxf(mx, __shfl_xor(mx, o, 64));
    float e[4], sum = 0.f;
    #pragma unroll
    for (int i = 0; i < 4; ++i) { e[i] = __expf(v[i] - mx); sum += e[i]; }
    #pragma unroll
    for (int o = 32; o; o >>= 1) sum += __shfl_xor(sum, o, 64);
    const float inv = 1.f / sum;
    #pragma unroll
    for (int i = 0; i < 4; ++i)
        attn2[(size_t)row * 256 + lane + i * 64] = f2bf(e[i] * inv);
}

// ---------------------------------------------------------------------------
extern "C" void kernel_launch(void* const* d_in, const int* in_sizes, int n_in,
                              void* d_out, int out_size, void* d_ws, size_t ws_size,
                              hipStream_t stream) {
    const float* x     = (const float*)d_in[0];   // [8,16,256,512]
    const float* w_qkv = (const float*)d_in[1];   // [512,1536]
    const float* pos   = (const float*)d_in[2];   // [1,16,256,256]
    const float* w1    = (const float*)d_in[3];   // [256,256]
    const float* b1    = (const float*)d_in[4];   // [256]
    const float* w2    = (const float*)d_in[5];   // [256]
    const float* b2    = (const float*)d_in[6];   // [1]
    const float* w_out = (const float*)d_in[7];   // [512,512]
    const float* b_out = (const float*)d_in[8];   // [512]
    float* out = (float*)d_out;
    char* ws = (char*)d_ws;

    // lifetime-audited workspace (regions reused sequentially):
    u16*   xb    = (u16*)(ws);                    // [0,32M)    stages 0->1
    u16*   vT    = (u16*)(ws);                    // [0,32M)    1b->7 (xb dead)
    u16*   qb    = (u16*)(ws + 33554432);         // [32,64M)   1->2
    u16*   hbuf  = (u16*)(ws + 33554432);         // [32,48M)   4->5 (q dead)
    u16*   attn2 = (u16*)(ws + 50331648);         // [48,64M)   6->7
    u16*   kb    = (u16*)(ws + 67108864);         // [64,96M)   1->2
    u16*   attn  = (u16*)(ws + 67108864);         // [64,80M)   3->6 (k dead)
    u16*   vb    = (u16*)(ws + 100663296);        // [96,128M)  1->1b
    float* S     = (float*)(ws + 100663296);      // [96,128M)  2->3 (v dead)
    u16*   av    = (u16*)(ws + 100663296);        // [96,128M)  7->8 (S dead)
    float* wrow  = (float*)(ws + 134217728);
    u16*   wqkvT = (u16*)(ws + 134348800);        // [1536][512]
    u16*   w1T   = (u16*)(ws + 135921664);        // [256][256]
    u16*   woT   = (u16*)(ws + 136052736);        // [512][512]
    if (ws_size < (size_t)136577024) return;

    dim3 blk(256);

    // 0. convert / transpose to bf16
    conv_b_k<<<dim3(8192), blk, 0, stream>>>(x, xb, 2097152);
    trans_f2b_k<<<dim3(24, 8), blk, 0, stream>>>(w_qkv, wqkvT, 512, 1536);
    trans_f2b_k<<<dim3(4, 4), blk, 0, stream>>>(w1, w1T, 256, 256);
    trans_f2b_k<<<dim3(8, 8), blk, 0, stream>>>(w_out, woT, 512, 512);

    // 1. q/k/v = x @ w_qkv (three N=512 slices; B = wqkvT rows)
    gemm2_k<0, false, false, false><<<dim3(256, 4, 1), blk, 0, stream>>>(
        xb, wqkvT,          qb, nullptr, nullptr, 1.f, 512, 512, 512, 512, 0, 0, 0);
    gemm2_k<0, false, false, false><<<dim3(256, 4, 1), blk, 0, stream>>>(
        xb, wqkvT + 262144, kb, nullptr, nullptr, 1.f, 512, 512, 512, 512, 0, 0, 0);
    gemm2_k<0, false, false, false><<<dim3(256, 4, 1), blk, 0, stream>>>(
        xb, wqkvT + 524288, vb, nullptr, nullptr, 1.f, 512, 512, 512, 512, 0, 0, 0);

    // 1b. vT[bc] = v[bc]^T   ([256][512] -> [512][256])
    trans_b2b_k<<<dim3(8, 4, 128), blk, 0, stream>>>(vb, vT, 512, 256, 131072L, 131072L);

    // 2. S = 0.125 * q @ k^T (per b,c)
    gemm2_k<0, true, false, false><<<dim3(2, 2, 128), blk, 0, stream>>>(
        qb, kb, S, nullptr, nullptr, 0.125f, 512, 512, 512, 256, 131072L, 131072L, 65536L);

    // 3. attn = softmax(S)
    softmax1_k<<<dim3(8192), blk, 0, stream>>>(S, attn);

    // 4. h = relu((attn + pos) @ w1 + b1)   (pos-add fused into A staging)
    gemm2_k<1, false, true, true><<<dim3(2, 2, 128), blk, 0, stream>>>(
        attn, w1T, hbuf, b1, pos, 1.f, 256, 256, 256, 256, 65536L, 0L, 65536L);

    // 5. wrow = h @ w2 + b2
    wrow_k<<<dim3(8192), blk, 0, stream>>>(hbuf, w2, b2, wrow);

    // 6. attn2 = softmax(attn * gaussian-decay(wrow))
    attn2_k<<<dim3(8192), blk, 0, stream>>>(attn, wrow, attn2);

    // 7. av = attn2 @ v  (B = vT)
    gemm2_k<0, false, false, false><<<dim3(2, 4, 128), blk, 0, stream>>>(
        attn2, vT, av, nullptr, nullptr, 1.f, 256, 256, 256, 512, 65536L, 131072L, 131072L);

    // 8. out = av @ w_out + b_out  (B = w_outT)
    gemm2_k<0, true, false, true><<<dim3(256, 4, 1), blk, 0, stream>>>(
        av, woT, out, b_out, nullptr, 1.f, 512, 512, 512, 512, 0, 0, 0);
}

// Round 5
// 337.728 us; speedup vs baseline: 1.6042x; 1.1278x over previous
//
#include <hip/hip_runtime.h>
#include <hip/hip_bf16.h>

typedef unsigned short u16;
typedef unsigned int u32;

typedef short bf16x8 __attribute__((ext_vector_type(8)));
typedef float f32x4 __attribute__((ext_vector_type(4)));

__device__ __forceinline__ u16 f2bf(float f) {
    union { float f; u32 u; } v; v.f = f;
    u32 u = v.u;
    return (u16)((u + 0x7fffu + ((u >> 16) & 1u)) >> 16);
}
__device__ __forceinline__ float bf2f(u16 b) {
    union { u32 u; float f; } v; v.u = ((u32)b) << 16;
    return v.f;
}

// async global->LDS 16B: lane l of the wave lands at uniform_base + l*16B.
__device__ __forceinline__ void gload16(const u16* g, u16* lds_uniform_base, int lane) {
#if __has_builtin(__builtin_amdgcn_global_load_lds)
    __builtin_amdgcn_global_load_lds((const __attribute__((address_space(1))) void*)g,
                                     (__attribute__((address_space(3))) void*)lds_uniform_base,
                                     16, 0, 0);
#else
    *(int4*)(lds_uniform_base + lane * 8) = *(const int4*)g;
#endif
}

// ---------------------------------------------------------------------------
// bf16 MFMA GEMM (QKV only now), 128x128 tile, BK=32, 4 waves, verified r4.
// ---------------------------------------------------------------------------
template<int AMODE, bool OUT_F32, bool RELU, bool HAS_BIAS>
__global__ __launch_bounds__(256) void gemm2_k(
    const u16* __restrict__ A, const u16* __restrict__ B, void* __restrict__ Cp,
    const float* __restrict__ bias, const float* __restrict__ pos, float scale,
    int K, int lda, int ldb, int ldc, long sA, long sB, long sC)
{
    __shared__ u16 As[128 * 32];
    __shared__ u16 Bs[128 * 32];

    const int tid   = threadIdx.x;
    const int lane  = tid & 63;
    const int wave  = tid >> 6;
    const int wm = (wave >> 1) * 64, wn = (wave & 1) * 64;
    const int row0 = blockIdx.x * 128;
    const int col0 = blockIdx.y * 128;
    const long batch = blockIdx.z;

    const u16* Ab = A + batch * sA;
    const u16* Bb = B + batch * sB;

    const int slotp = (lane >> 4) ^ (lane & 3) ^ ((lane >> 2) & 3);

    f32x4 acc[4][4] = {};

    for (int k0 = 0; k0 < K; k0 += 32) {
        #pragma unroll
        for (int i = 0; i < 2; ++i) {
            int idx = tid + i * 256;
            int r = idx >> 2, c = idx & 3;
            int s = c ^ (r & 3) ^ ((r >> 2) & 3);
            gload16(Ab + (size_t)(row0 + r) * lda + k0 + s * 8,
                    &As[(idx & ~63) * 8], lane);
        }
        #pragma unroll
        for (int i = 0; i < 2; ++i) {
            int idx = tid + i * 256;
            int r = idx >> 2, c = idx & 3;
            int s = c ^ (r & 3) ^ ((r >> 2) & 3);
            gload16(Bb + (size_t)(col0 + r) * ldb + k0 + s * 8,
                    &Bs[(idx & ~63) * 8], lane);
        }
        __syncthreads();

        bf16x8 a[4], b[4];
        #pragma unroll
        for (int m = 0; m < 4; ++m)
            a[m] = *(const bf16x8*)&As[(wm + m * 16 + (lane & 15)) * 32 + slotp * 8];
        #pragma unroll
        for (int n = 0; n < 4; ++n)
            b[n] = *(const bf16x8*)&Bs[(wn + n * 16 + (lane & 15)) * 32 + slotp * 8];
        #pragma unroll
        for (int m = 0; m < 4; ++m)
            #pragma unroll
            for (int n = 0; n < 4; ++n)
                acc[m][n] = __builtin_amdgcn_mfma_f32_16x16x32_bf16(a[m], b[n], acc[m][n], 0, 0, 0);
        __syncthreads();
    }

    float* Cf = (float*)Cp + batch * sC;
    u16*   Cb = (u16*)Cp + batch * sC;
    #pragma unroll
    for (int m = 0; m < 4; ++m) {
        #pragma unroll
        for (int n = 0; n < 4; ++n) {
            #pragma unroll
            for (int r = 0; r < 4; ++r) {
                int row = row0 + wm + m * 16 + ((lane >> 4)) * 4 + r;
                int col = col0 + wn + n * 16 + (lane & 15);
                float v = acc[m][n][r] * scale;
                if constexpr (HAS_BIAS) v += bias[col];
                if constexpr (RELU) v = fmaxf(v, 0.f);
                if constexpr (OUT_F32) Cf[(size_t)row * ldc + col] = v;
                else                   Cb[(size_t)row * ldc + col] = f2bf(v);
            }
        }
    }
}

// ---------------------------------------------------------------------------
// fused back-half helpers
// ---------------------------------------------------------------------------
__device__ __forceinline__ void stage_b256(const u16* __restrict__ src, int ld, int k0,
                                           u16* Bs, int tid, int lane) {
    #pragma unroll
    for (int i = 0; i < 2; ++i) {
        int idx = tid + i * 512;
        int r = idx >> 2, c = idx & 3;
        int s = c ^ (r & 3) ^ ((r >> 2) & 3);
        gload16(src + (size_t)r * ld + k0 + s * 8, &Bs[(idx & ~63) * 8], lane);
    }
}

// read one A-frag (16B) from the big W tile; chunk-XOR-swizzled storage
__device__ __forceinline__ bf16x8 rdW(const u16* W, int row, int chunk) {
    return *(const bf16x8*)&W[row * 512 + (chunk ^ (row & 7)) * 8];
}
__device__ __forceinline__ void wrW(u16* W, int row, int col, u16 v) {
    W[row * 512 + (((col >> 3) ^ (row & 7)) * 8) + (col & 7)] = v;
}

// C = A(W-tile) @ B^T, M=128 (8 waves 2x4), N=256, BK=32; B streamed via gload.
__device__ __forceinline__ void gemm_from_W(
    f32x4 (&dst)[4][4], const u16* __restrict__ Bsrc, int ldb, int K, int cbase,
    const u16* W, u16* Bs, int tid, int lane, int wm, int wn, int l15, int l4, int slotp)
{
    #pragma unroll
    for (int m = 0; m < 4; ++m)
        #pragma unroll
        for (int n = 0; n < 4; ++n) dst[m][n] = f32x4{0.f, 0.f, 0.f, 0.f};
    for (int k0 = 0; k0 < K; k0 += 32) {
        stage_b256(Bsrc, ldb, k0, Bs, tid, lane);
        __syncthreads();
        bf16x8 a[4], b[4];
        #pragma unroll
        for (int m = 0; m < 4; ++m)
            a[m] = rdW(W, wm + m * 16 + l15, cbase + (k0 >> 3) + l4);
        #pragma unroll
        for (int n = 0; n < 4; ++n)
            b[n] = *(const bf16x8*)&Bs[(wn + n * 16 + l15) * 32 + slotp * 8];
        #pragma unroll
        for (int m = 0; m < 4; ++m)
            #pragma unroll
            for (int n = 0; n < 4; ++n)
                dst[m][n] = __builtin_amdgcn_mfma_f32_16x16x32_bf16(a[m], b[n], dst[m][n], 0, 0, 0);
        __syncthreads();
    }
}

// in-place row softmax over val (rows wm+m*16+l4*4+rr, 256 cols across 4 waves)
__device__ __forceinline__ void row_softmax(
    f32x4 (&val)[4][4], float (&red)[128][4], int wm, int wnidx, int l15, int l4)
{
    float rm[4][4];
    #pragma unroll
    for (int m = 0; m < 4; ++m)
        #pragma unroll
        for (int rr = 0; rr < 4; ++rr) {
            float x = fmaxf(fmaxf(val[m][0][rr], val[m][1][rr]),
                            fmaxf(val[m][2][rr], val[m][3][rr]));
            #pragma unroll
            for (int o = 1; o < 16; o <<= 1) x = fmaxf(x, __shfl_xor(x, o, 64));
            rm[m][rr] = x;
        }
    if (l15 == 0)
        #pragma unroll
        for (int m = 0; m < 4; ++m)
            #pragma unroll
            for (int rr = 0; rr < 4; ++rr)
                red[wm + m * 16 + l4 * 4 + rr][wnidx] = rm[m][rr];
    __syncthreads();
    #pragma unroll
    for (int m = 0; m < 4; ++m)
        #pragma unroll
        for (int rr = 0; rr < 4; ++rr) {
            float4 rv = *(const float4*)&red[wm + m * 16 + l4 * 4 + rr][0];
            rm[m][rr] = fmaxf(fmaxf(rv.x, rv.y), fmaxf(rv.z, rv.w));
        }
    __syncthreads();
    float rs[4][4];
    #pragma unroll
    for (int m = 0; m < 4; ++m)
        #pragma unroll
        for (int rr = 0; rr < 4; ++rr) {
            float s = 0.f;
            #pragma unroll
            for (int n = 0; n < 4; ++n) {
                float e = __expf(val[m][n][rr] - rm[m][rr]);
                val[m][n][rr] = e;
                s += e;
            }
            #pragma unroll
            for (int o = 1; o < 16; o <<= 1) s += __shfl_xor(s, o, 64);
            rs[m][rr] = s;
        }
    if (l15 == 0)
        #pragma unroll
        for (int m = 0; m < 4; ++m)
            #pragma unroll
            for (int rr = 0; rr < 4; ++rr)
                red[wm + m * 16 + l4 * 4 + rr][wnidx] = rs[m][rr];
    __syncthreads();
    #pragma unroll
    for (int m = 0; m < 4; ++m)
        #pragma unroll
        for (int rr = 0; rr < 4; ++rr) {
            float4 rv = *(const float4*)&red[wm + m * 16 + l4 * 4 + rr][0];
            float inv = 1.f / (rv.x + rv.y + rv.z + rv.w);
            #pragma unroll
            for (int n = 0; n < 4; ++n) val[m][n][rr] *= inv;
        }
    __syncthreads();
}

// ---------------------------------------------------------------------------
// Megakernel: stages 2..8 fused. grid (2 m-tiles, 128 bc), 512 threads.
// ---------------------------------------------------------------------------
__global__ __launch_bounds__(512, 2) void fused_k(
    const u16* __restrict__ qb, const u16* __restrict__ kb, const u16* __restrict__ vT,
    const u16* __restrict__ w1T, const u16* __restrict__ woT,
    const float* __restrict__ pos, const float* __restrict__ b1v,
    const float* __restrict__ w2v, const float* __restrict__ b2v,
    const float* __restrict__ bov, float* __restrict__ out)
{
    __shared__ u16 As[128 * 32];     // 8 KB   (P1 q staging)
    __shared__ u16 Bs[256 * 32];     // 16 KB  (B staging, all phases)
    __shared__ u16 W[128 * 512];     // 128 KB (attnw | attn2, then av)
    __shared__ float red[128][4];
    __shared__ float wr[128];

    const int tid  = threadIdx.x;
    const int lane = tid & 63;
    const int wid  = tid >> 6;
    const int wm = (wid >> 2) * 64;
    const int wn = (wid & 3) * 64;
    const int l15 = lane & 15, l4 = lane >> 4;
    const int slotp = l4 ^ (lane & 3) ^ ((lane >> 2) & 3);
    const int row0 = blockIdx.x * 128;
    const int z    = blockIdx.y;

    const u16* q = qb + (size_t)z * 131072 + (size_t)row0 * 512;
    const u16* k = kb + (size_t)z * 131072;
    const u16* v = vT + (size_t)z * 131072;
    const float* posb = pos + (size_t)(z & 15) * 65536 + (size_t)row0 * 256;
    const float b2s = b2v[0];

    f32x4 sa[4][4] = {};
    f32x4 acc[4][4] = {};

    // ---- P1: S = 0.125 * q @ k^T  (K=512) ----
    for (int k0 = 0; k0 < 512; k0 += 32) {
        {
            int r = tid >> 2, c = tid & 3;
            int s = c ^ (r & 3) ^ ((r >> 2) & 3);
            gload16(q + (size_t)r * 512 + k0 + s * 8, &As[(tid & ~63) * 8], lane);
        }
        stage_b256(k, 512, k0, Bs, tid, lane);
        __syncthreads();
        bf16x8 a[4], b[4];
        #pragma unroll
        for (int m = 0; m < 4; ++m)
            a[m] = *(const bf16x8*)&As[(wm + m * 16 + l15) * 32 + slotp * 8];
        #pragma unroll
        for (int n = 0; n < 4; ++n)
            b[n] = *(const bf16x8*)&Bs[(wn + n * 16 + l15) * 32 + slotp * 8];
        #pragma unroll
        for (int m = 0; m < 4; ++m)
            #pragma unroll
            for (int n = 0; n < 4; ++n)
                sa[m][n] = __builtin_amdgcn_mfma_f32_16x16x32_bf16(a[m], b[n], sa[m][n], 0, 0, 0);
        __syncthreads();
    }

    // ---- P2: softmax #1 (fp32, in-reg) ; W[:,0:256) = bf16(attn + pos) ----
    #pragma unroll
    for (int m = 0; m < 4; ++m)
        #pragma unroll
        for (int n = 0; n < 4; ++n) sa[m][n] *= 0.125f;
    row_softmax(sa, red, wm, wid & 3, l15, l4);
    #pragma unroll
    for (int m = 0; m < 4; ++m)
        #pragma unroll
        for (int rr = 0; rr < 4; ++rr) {
            int row = wm + m * 16 + l4 * 4 + rr;
            #pragma unroll
            for (int n = 0; n < 4; ++n) {
                int col = wn + n * 16 + l15;
                wrW(W, row, col, f2bf(sa[m][n][rr] + posb[row * 256 + col]));
            }
        }
    // (first sync inside P3's gemm_from_W covers W write->read)

    // ---- P3: h = relu(attnw @ w1 + b1); wrow = h . w2 + b2 (h never stored) ----
    float b1c[4], w2c[4];
    #pragma unroll
    for (int n = 0; n < 4; ++n) {
        int col = wn + n * 16 + l15;
        b1c[n] = b1v[col];
        w2c[n] = w2v[col];
    }
    gemm_from_W(acc, w1T, 256, 256, 0, W, Bs, tid, lane, wm, wn, l15, l4, slotp);
    {
        float part[4][4];
        #pragma unroll
        for (int m = 0; m < 4; ++m)
            #pragma unroll
            for (int rr = 0; rr < 4; ++rr) {
                float p = 0.f;
                #pragma unroll
                for (int n = 0; n < 4; ++n)
                    p += fmaxf(acc[m][n][rr] + b1c[n], 0.f) * w2c[n];
                #pragma unroll
                for (int o = 1; o < 16; o <<= 1) p += __shfl_xor(p, o, 64);
                part[m][rr] = p;
            }
        if (l15 == 0)
            #pragma unroll
            for (int m = 0; m < 4; ++m)
                #pragma unroll
                for (int rr = 0; rr < 4; ++rr)
                    red[wm + m * 16 + l4 * 4 + rr][wid & 3] = part[m][rr];
        __syncthreads();
        if ((wid & 3) == 0 && l15 == 0)
            #pragma unroll
            for (int m = 0; m < 4; ++m)
                #pragma unroll
                for (int rr = 0; rr < 4; ++rr) {
                    int row = wm + m * 16 + l4 * 4 + rr;
                    float4 rv = *(const float4*)&red[row][0];
                    wr[row] = rv.x + rv.y + rv.z + rv.w + b2s;
                }
        __syncthreads();
    }

    // ---- P4: attn2 = softmax(attn * gaussian(wrow)) ; W[:,256:512) = bf16 ----
    #pragma unroll
    for (int m = 0; m < 4; ++m)
        #pragma unroll
        for (int rr = 0; rr < 4; ++rr) {
            int row = wm + m * 16 + l4 * 4 + rr;
            float wv = wr[row];
            float idn = 1.f / (2.f * wv * wv + 1e-6f);
            int rg = row0 + row;
            #pragma unroll
            for (int n = 0; n < 4; ++n) {
                float d = (float)(wn + n * 16 + l15 - rg);
                sa[m][n][rr] *= __expf(-d * d * idn);
            }
        }
    row_softmax(sa, red, wm, wid & 3, l15, l4);
    #pragma unroll
    for (int m = 0; m < 4; ++m)
        #pragma unroll
        for (int rr = 0; rr < 4; ++rr) {
            int row = wm + m * 16 + l4 * 4 + rr;
            #pragma unroll
            for (int n = 0; n < 4; ++n)
                wrW(W, row, 256 + wn + n * 16 + l15, f2bf(sa[m][n][rr]));
        }

    // ---- P5: av = attn2 @ v  (two 256-col halves -> sa, acc regs) ----
    gemm_from_W(sa,  v,                  256, 256, 32, W, Bs, tid, lane, wm, wn, l15, l4, slotp);
    gemm_from_W(acc, v + 256 * 256,      256, 256, 32, W, Bs, tid, lane, wm, wn, l15, l4, slotp);

    // ---- P5b: W <- av (bf16, both halves; attnw/attn2 dead) ----
    #pragma unroll
    for (int m = 0; m < 4; ++m)
        #pragma unroll
        for (int rr = 0; rr < 4; ++rr) {
            int row = wm + m * 16 + l4 * 4 + rr;
            #pragma unroll
            for (int n = 0; n < 4; ++n) {
                int col = wn + n * 16 + l15;
                wrW(W, row, col,       f2bf(sa[m][n][rr]));
                wrW(W, row, col + 256, f2bf(acc[m][n][rr]));
            }
        }

    // ---- P6: out = av @ w_out + b_out  (K=512, two 256-col passes) ----
    for (int np = 0; np < 2; ++np) {
        gemm_from_W(acc, woT + (size_t)np * 256 * 512, 512, 512, 0,
                    W, Bs, tid, lane, wm, wn, l15, l4, slotp);
        float boc[4];
        #pragma unroll
        for (int n = 0; n < 4; ++n) boc[n] = bov[np * 256 + wn + n * 16 + l15];
        #pragma unroll
        for (int m = 0; m < 4; ++m)
            #pragma unroll
            for (int rr = 0; rr < 4; ++rr) {
                int row = row0 + wm + m * 16 + l4 * 4 + rr;
                size_t ob = ((size_t)z * 256 + row) * 512 + np * 256;
                #pragma unroll
                for (int n = 0; n < 4; ++n)
                    out[ob + wn + n * 16 + l15] = acc[m][n][rr] + boc[n];
            }
    }
}

// ---------------------------------------------------------------------------
// fp32 [R][C] -> bf16 [C][R] (weights)
// ---------------------------------------------------------------------------
__global__ __launch_bounds__(256) void trans_f2b_k(
    const float* __restrict__ in, u16* __restrict__ out, int R, int C)
{
    __shared__ u16 t[64][80];
    const int bx = blockIdx.x, by = blockIdx.y;
    const int tid = threadIdx.x;
    const int r = tid >> 2, c16 = (tid & 3) * 16;
    const float* ip = in + (size_t)(by * 64 + r) * C + bx * 64 + c16;
    #pragma unroll
    for (int j = 0; j < 4; ++j) {
        float4 vv = *(const float4*)(ip + j * 4);
        t[r][c16 + j * 4 + 0] = f2bf(vv.x);
        t[r][c16 + j * 4 + 1] = f2bf(vv.y);
        t[r][c16 + j * 4 + 2] = f2bf(vv.z);
        t[r][c16 + j * 4 + 3] = f2bf(vv.w);
    }
    __syncthreads();
    const int orow = tid >> 2, oc = (tid & 3) * 16;
    u16 o[16];
    #pragma unroll
    for (int j = 0; j < 16; ++j) o[j] = t[oc + j][orow];
    u16* op = out + (size_t)(bx * 64 + orow) * R + by * 64 + oc;
    *(int4*)op       = *(const int4*)&o[0];
    *(int4*)(op + 8) = *(const int4*)&o[8];
}

// bf16 [R][C] -> bf16 [C][R], batched (v -> vT)
__global__ __launch_bounds__(256) void trans_b2b_k(
    const u16* __restrict__ in, u16* __restrict__ out,
    int ldin, int R, long sIn, long sOut)
{
    __shared__ u16 t[64][80];
    const int bx = blockIdx.x, by = blockIdx.y;
    const long zz = blockIdx.z;
    const u16* ip = in + zz * sIn;
    u16* op = out + zz * sOut;
    const int tid = threadIdx.x;
    const int r = tid >> 2, c16 = (tid & 3) * 16;
    const u16* src = ip + (size_t)(by * 64 + r) * ldin + bx * 64 + c16;
    *(int4*)&t[r][c16]     = *(const int4*)src;
    *(int4*)&t[r][c16 + 8] = *(const int4*)(src + 8);
    __syncthreads();
    const int orow = tid >> 2, oc = (tid & 3) * 16;
    u16 o[16];
    #pragma unroll
    for (int j = 0; j < 16; ++j) o[j] = t[oc + j][orow];
    u16* dst = op + (size_t)(bx * 64 + orow) * R + by * 64 + oc;
    *(int4*)dst       = *(const int4*)&o[0];
    *(int4*)(dst + 8) = *(const int4*)&o[8];
}

// fp32 -> bf16 flat convert
__global__ __launch_bounds__(256) void conv_b_k(
    const float* __restrict__ in, u16* __restrict__ out, int n8)
{
    int i = blockIdx.x * 256 + threadIdx.x;
    if (i >= n8) return;
    float4 a = ((const float4*)in)[i * 2], b = ((const float4*)in)[i * 2 + 1];
    u16 o[8] = { f2bf(a.x), f2bf(a.y), f2bf(a.z), f2bf(a.w),
                 f2bf(b.x), f2bf(b.y), f2bf(b.z), f2bf(b.w) };
    ((int4*)out)[i] = *(const int4*)o;
}

// ---------------------------------------------------------------------------
extern "C" void kernel_launch(void* const* d_in, const int* in_sizes, int n_in,
                              void* d_out, int out_size, void* d_ws, size_t ws_size,
                              hipStream_t stream) {
    const float* x     = (const float*)d_in[0];
    const float* w_qkv = (const float*)d_in[1];
    const float* pos   = (const float*)d_in[2];
    const float* w1    = (const float*)d_in[3];
    const float* b1    = (const float*)d_in[4];
    const float* w2    = (const float*)d_in[5];
    const float* b2    = (const float*)d_in[6];
    const float* w_out = (const float*)d_in[7];
    const float* b_out = (const float*)d_in[8];
    float* out = (float*)d_out;
    char* ws = (char*)d_ws;

    // workspace (lifetimes): xb dead after QKV; vT overlays xb.
    u16* xb    = (u16*)(ws);                      // [0,32M)
    u16* vT    = (u16*)(ws);                      // [0,32M)  after xb dead
    u16* qkvb  = (u16*)(ws + 33554432);           // [32,128M) q|k|v, 32M each
    u16* wqkvT = (u16*)(ws + 134217728);          // 1.5 MB
    u16* w1T   = (u16*)(ws + 135790592);          // 128 KB
    u16* woT   = (u16*)(ws + 135921664);          // 512 KB -> end 136445952
    if (ws_size < (size_t)136445952) return;

    u16* qb = qkvb;
    u16* kb = qkvb + 16777216;
    u16* vb = qkvb + 33554432;

    dim3 blk(256);

    // 0. convert / transpose weights + x to bf16
    conv_b_k<<<dim3(8192), blk, 0, stream>>>(x, xb, 2097152);
    trans_f2b_k<<<dim3(24, 8), blk, 0, stream>>>(w_qkv, wqkvT, 512, 1536);
    trans_f2b_k<<<dim3(4, 4), blk, 0, stream>>>(w1, w1T, 256, 256);
    trans_f2b_k<<<dim3(8, 8), blk, 0, stream>>>(w_out, woT, 512, 512);

    // 1. q/k/v = x @ w_qkv  (z selects slice)
    gemm2_k<0, false, false, false><<<dim3(256, 4, 3), blk, 0, stream>>>(
        xb, wqkvT, qkvb, nullptr, nullptr, 1.f, 512, 512, 512, 512,
        0L, 262144L, 16777216L);

    // 1b. vT[bc] = v[bc]^T
    trans_b2b_k<<<dim3(8, 4, 128), blk, 0, stream>>>(vb, vT, 512, 256, 131072L, 131072L);

    // 2-8. fused attention back-half
    fused_k<<<dim3(2, 128), dim3(512), 0, stream>>>(
        qb, kb, vT, w1T, woT, pos, b1, w2, b2, b_out, out);
}

// Round 6
// 334.710 us; speedup vs baseline: 1.6186x; 1.0090x over previous
//
#include <hip/hip_runtime.h>
#include <hip/hip_bf16.h>

typedef unsigned short u16;
typedef unsigned int u32;

typedef short bf16x8 __attribute__((ext_vector_type(8)));
typedef float f32x4 __attribute__((ext_vector_type(4)));

__device__ __forceinline__ u16 f2bf(float f) {
    union { float f; u32 u; } v; v.f = f;
    u32 u = v.u;
    return (u16)((u + 0x7fffu + ((u >> 16) & 1u)) >> 16);
}
__device__ __forceinline__ float bf2f(u16 b) {
    union { u32 u; float f; } v; v.u = ((u32)b) << 16;
    return v.f;
}

// async global->LDS 16B: lane l of the wave lands at uniform_base + l*16B.
__device__ __forceinline__ void gload16(const u16* g, u16* lds_uniform_base, int lane) {
#if __has_builtin(__builtin_amdgcn_global_load_lds)
    __builtin_amdgcn_global_load_lds((const __attribute__((address_space(1))) void*)g,
                                     (__attribute__((address_space(3))) void*)lds_uniform_base,
                                     16, 0, 0);
#else
    *(int4*)(lds_uniform_base + lane * 8) = *(const int4*)g;
#endif
}

#define MFMA_BF16 __builtin_amdgcn_mfma_f32_16x16x32_bf16

// ---------------------------------------------------------------------------
// QKV GEMM: C = A @ B^T, A[32768,512], B = wqkvT slice [512,512] (z picks q/k/v)
// 128x128 tile, BK=32, 4 waves, 2-phase double-buffered staging.
// ---------------------------------------------------------------------------
__global__ __launch_bounds__(256) void qkv_k(
    const u16* __restrict__ A, const u16* __restrict__ B, u16* __restrict__ C)
{
    __shared__ u16 As[2][4096];
    __shared__ u16 Bs[2][4096];
    const int tid  = threadIdx.x;
    const int lane = tid & 63;
    const int wave = tid >> 6;
    const int wm = (wave >> 1) * 64, wn = (wave & 1) * 64;
    const int row0 = blockIdx.x * 128;
    const int col0 = blockIdx.y * 128;
    const u16* Bb = B + (size_t)blockIdx.z * 262144;
    u16* Cb = C + (size_t)blockIdx.z * 16777216;
    const int l15 = lane & 15, l4 = lane >> 4;
    const int slotp = l4 ^ (lane & 3) ^ ((lane >> 2) & 3);

    f32x4 acc[4][4] = {};

    // stage one 128x32 A-tile and B-tile into buffer `buf`
    auto stage = [&](int buf, int k0) {
        #pragma unroll
        for (int i = 0; i < 2; ++i) {
            int idx = tid + i * 256;
            int r = idx >> 2, c = idx & 3;
            int s = c ^ (r & 3) ^ ((r >> 2) & 3);
            gload16(A + (size_t)(row0 + r) * 512 + k0 + s * 8, &As[buf][(idx & ~63) * 8], lane);
        }
        #pragma unroll
        for (int i = 0; i < 2; ++i) {
            int idx = tid + i * 256;
            int r = idx >> 2, c = idx & 3;
            int s = c ^ (r & 3) ^ ((r >> 2) & 3);
            gload16(Bb + (size_t)(col0 + r) * 512 + k0 + s * 8, &Bs[buf][(idx & ~63) * 8], lane);
        }
    };

    stage(0, 0);
    __syncthreads();
    for (int t = 0; t < 16; ++t) {
        int cur = t & 1;
        if (t < 15) stage(cur ^ 1, (t + 1) * 32);   // prefetch next tile first
        bf16x8 a[4], b[4];
        #pragma unroll
        for (int m = 0; m < 4; ++m)
            a[m] = *(const bf16x8*)&As[cur][(wm + m * 16 + l15) * 32 + slotp * 8];
        #pragma unroll
        for (int n = 0; n < 4; ++n)
            b[n] = *(const bf16x8*)&Bs[cur][(wn + n * 16 + l15) * 32 + slotp * 8];
        #pragma unroll
        for (int m = 0; m < 4; ++m)
            #pragma unroll
            for (int n = 0; n < 4; ++n)
                acc[m][n] = MFMA_BF16(a[m], b[n], acc[m][n], 0, 0, 0);
        __syncthreads();
    }

    #pragma unroll
    for (int m = 0; m < 4; ++m)
        #pragma unroll
        for (int n = 0; n < 4; ++n)
            #pragma unroll
            for (int r = 0; r < 4; ++r)
                Cb[(size_t)(row0 + wm + m * 16 + l4 * 4 + r) * 512 + col0 + wn + n * 16 + l15]
                    = f2bf(acc[m][n][r]);
}

// ---------------------------------------------------------------------------
// fused helpers (64-row tile, 256 threads, 4 waves all-N)
// ---------------------------------------------------------------------------
__device__ __forceinline__ void stageB256(const u16* __restrict__ src, int ld, int k0,
                                          u16* buf, int tid, int lane) {
    #pragma unroll
    for (int i = 0; i < 4; ++i) {
        int idx = tid + i * 256;
        int r = idx >> 2, c = idx & 3;
        int s = c ^ (r & 3) ^ ((r >> 2) & 3);
        gload16(src + (size_t)r * ld + k0 + s * 8, &buf[(idx & ~63) * 8], lane);
    }
}
__device__ __forceinline__ void stageA64(const u16* __restrict__ src, int k0,
                                         u16* buf, int tid, int lane) {
    int r = tid >> 2, c = tid & 3;
    int s = c ^ (r & 3) ^ ((r >> 2) & 3);
    gload16(src + (size_t)r * 512 + k0 + s * 8, &buf[(tid & ~63) * 8], lane);
}

// W tile 64x256 bf16, chunk-XOR swizzle within 8-chunk groups (involution)
__device__ __forceinline__ int wswz(int row, int chunk) {
    return (chunk & 24) | ((chunk ^ row) & 7);
}
__device__ __forceinline__ bf16x8 rdW(const u16* W, int row, int chunk) {
    return *(const bf16x8*)&W[row * 256 + wswz(row, chunk) * 8];
}
__device__ __forceinline__ void wrW(u16* W, int row, int col, u16 v) {
    W[row * 256 + wswz(row, col >> 3) * 8 + (col & 7)] = v;
}

// dst (+)= W(64xK) @ B^T(256xK), BK=32, 2-phase double-buffered B staging.
template<bool INIT>
__device__ __forceinline__ void gemm_from_W(
    f32x4 (&dst)[4][4], const u16* __restrict__ Bsrc, int ldb, int K,
    const u16* __restrict__ W, u16 (&Bs)[2][8192],
    int tid, int lane, int wn, int l15, int l4, int slotp)
{
    if (INIT)
        #pragma unroll
        for (int m = 0; m < 4; ++m)
            #pragma unroll
            for (int n = 0; n < 4; ++n) dst[m][n] = f32x4{0.f, 0.f, 0.f, 0.f};
    stageB256(Bsrc, ldb, 0, Bs[0], tid, lane);
    __syncthreads();
    const int nt = K >> 5;
    for (int t = 0; t < nt; ++t) {
        int cur = t & 1;
        if (t + 1 < nt) stageB256(Bsrc, ldb, (t + 1) * 32, Bs[cur ^ 1], tid, lane);
        bf16x8 a[4], b[4];
        #pragma unroll
        for (int m = 0; m < 4; ++m)
            a[m] = rdW(W, m * 16 + l15, t * 4 + l4);
        #pragma unroll
        for (int n = 0; n < 4; ++n)
            b[n] = *(const bf16x8*)&Bs[cur][(wn + n * 16 + l15) * 32 + slotp * 8];
        #pragma unroll
        for (int m = 0; m < 4; ++m)
            #pragma unroll
            for (int n = 0; n < 4; ++n)
                dst[m][n] = MFMA_BF16(a[m], b[n], dst[m][n], 0, 0, 0);
        __syncthreads();
    }
}

// in-place row softmax; rows m*16+l4*4+rr (64), cols split 4 waves x 64
__device__ __forceinline__ void row_softmax(
    f32x4 (&val)[4][4], float (&red)[64][4], int wid, int l15, int l4)
{
    float rm[4][4];
    #pragma unroll
    for (int m = 0; m < 4; ++m)
        #pragma unroll
        for (int rr = 0; rr < 4; ++rr) {
            float x = fmaxf(fmaxf(val[m][0][rr], val[m][1][rr]),
                            fmaxf(val[m][2][rr], val[m][3][rr]));
            #pragma unroll
            for (int o = 1; o < 16; o <<= 1) x = fmaxf(x, __shfl_xor(x, o, 64));
            rm[m][rr] = x;
        }
    if (l15 == 0)
        #pragma unroll
        for (int m = 0; m < 4; ++m)
            #pragma unroll
            for (int rr = 0; rr < 4; ++rr)
                red[m * 16 + l4 * 4 + rr][wid] = rm[m][rr];
    __syncthreads();
    #pragma unroll
    for (int m = 0; m < 4; ++m)
        #pragma unroll
        for (int rr = 0; rr < 4; ++rr) {
            float4 rv = *(const float4*)&red[m * 16 + l4 * 4 + rr][0];
            rm[m][rr] = fmaxf(fmaxf(rv.x, rv.y), fmaxf(rv.z, rv.w));
        }
    __syncthreads();
    float rs[4][4];
    #pragma unroll
    for (int m = 0; m < 4; ++m)
        #pragma unroll
        for (int rr = 0; rr < 4; ++rr) {
            float s = 0.f;
            #pragma unroll
            for (int n = 0; n < 4; ++n) {
                float e = __expf(val[m][n][rr] - rm[m][rr]);
                val[m][n][rr] = e;
                s += e;
            }
            #pragma unroll
            for (int o = 1; o < 16; o <<= 1) s += __shfl_xor(s, o, 64);
            rs[m][rr] = s;
        }
    if (l15 == 0)
        #pragma unroll
        for (int m = 0; m < 4; ++m)
            #pragma unroll
            for (int rr = 0; rr < 4; ++rr)
                red[m * 16 + l4 * 4 + rr][wid] = rs[m][rr];
    __syncthreads();
    #pragma unroll
    for (int m = 0; m < 4; ++m)
        #pragma unroll
        for (int rr = 0; rr < 4; ++rr) {
            float4 rv = *(const float4*)&red[m * 16 + l4 * 4 + rr][0];
            float inv = 1.f / (rv.x + rv.y + rv.z + rv.w);
            #pragma unroll
            for (int n = 0; n < 4; ++n) val[m][n][rr] *= inv;
        }
    __syncthreads();
}

// ---------------------------------------------------------------------------
// Megakernel stages 2..8. 64-row tile, grid(4,128), 256 thr, 73.3KB LDS
// -> 2 blocks/CU. XCD-swizzled block ids.
// ---------------------------------------------------------------------------
__global__ __launch_bounds__(256, 2) void fused_k(
    const u16* __restrict__ qb, const u16* __restrict__ kb, const u16* __restrict__ vT,
    const u16* __restrict__ w1T, const u16* __restrict__ woT,
    const float* __restrict__ pos, const float* __restrict__ b1v,
    const float* __restrict__ w2v, const float* __restrict__ b2v,
    const float* __restrict__ bov, float* __restrict__ out)
{
    __shared__ u16 As[2][2048];      // 8 KB  (P1 q staging)
    __shared__ u16 Bs[2][8192];      // 32 KB (B staging, all phases)
    __shared__ u16 W[64 * 256];      // 32 KB (attnw -> attn2 -> av halves)
    __shared__ float red[64][4];
    __shared__ float wr[64];

    const int tid  = threadIdx.x;
    const int lane = tid & 63;
    const int wid  = tid >> 6;                 // 0..3 = N quarter
    const int wn   = wid * 64;
    const int l15 = lane & 15, l4 = lane >> 4;
    const int slotp = l4 ^ (lane & 3) ^ ((lane >> 2) & 3);

    // XCD-aware bijective swizzle (512 blocks = 8 XCDs x 64)
    int hw = blockIdx.x + (blockIdx.y << 2);
    int wg = ((hw & 7) << 6) | (hw >> 3);
    const int row0 = (wg & 3) * 64;
    const int z    = wg >> 2;

    const u16* q = qb + (size_t)z * 131072 + (size_t)row0 * 512;
    const u16* k = kb + (size_t)z * 131072;
    const u16* v = vT + (size_t)z * 131072;
    const float* posb = pos + (size_t)(z & 15) * 65536 + (size_t)row0 * 256;
    const float b2s = b2v[0];

    f32x4 sa[4][4] = {};
    f32x4 acc[4][4];

    // ---- P1: S = q @ k^T (K=512), 2-phase dbuf ----
    stageA64(q, 0, As[0], tid, lane);
    stageB256(k, 512, 0, Bs[0], tid, lane);
    __syncthreads();
    for (int t = 0; t < 16; ++t) {
        int cur = t & 1;
        if (t < 15) {
            stageA64(q, (t + 1) * 32, As[cur ^ 1], tid, lane);
            stageB256(k, 512, (t + 1) * 32, Bs[cur ^ 1], tid, lane);
        }
        bf16x8 a[4], b[4];
        #pragma unroll
        for (int m = 0; m < 4; ++m)
            a[m] = *(const bf16x8*)&As[cur][(m * 16 + l15) * 32 + slotp * 8];
        #pragma unroll
        for (int n = 0; n < 4; ++n)
            b[n] = *(const bf16x8*)&Bs[cur][(wn + n * 16 + l15) * 32 + slotp * 8];
        #pragma unroll
        for (int m = 0; m < 4; ++m)
            #pragma unroll
            for (int n = 0; n < 4; ++n)
                sa[m][n] = MFMA_BF16(a[m], b[n], sa[m][n], 0, 0, 0);
        __syncthreads();
    }

    // ---- P2: softmax #1 ; W = bf16(attn + pos) ----
    #pragma unroll
    for (int m = 0; m < 4; ++m)
        #pragma unroll
        for (int n = 0; n < 4; ++n) sa[m][n] *= 0.125f;
    row_softmax(sa, red, wid, l15, l4);
    #pragma unroll
    for (int m = 0; m < 4; ++m)
        #pragma unroll
        for (int rr = 0; rr < 4; ++rr) {
            int row = m * 16 + l4 * 4 + rr;
            #pragma unroll
            for (int n = 0; n < 4; ++n) {
                int col = wn + n * 16 + l15;
                wrW(W, row, col, f2bf(sa[m][n][rr] + posb[row * 256 + col]));
            }
        }
    // (gemm entry barrier orders wrW before first W read)

    // ---- P3: h = relu(attnw @ w1 + b1); wrow = h . w2 + b2 ----
    float b1c[4], w2c[4];
    #pragma unroll
    for (int n = 0; n < 4; ++n) {
        int col = wn + n * 16 + l15;
        b1c[n] = b1v[col];
        w2c[n] = w2v[col];
    }
    gemm_from_W<true>(acc, w1T, 256, 256, W, Bs, tid, lane, wn, l15, l4, slotp);
    {
        float part[4][4];
        #pragma unroll
        for (int m = 0; m < 4; ++m)
            #pragma unroll
            for (int rr = 0; rr < 4; ++rr) {
                float p = 0.f;
                #pragma unroll
                for (int n = 0; n < 4; ++n)
                    p += fmaxf(acc[m][n][rr] + b1c[n], 0.f) * w2c[n];
                #pragma unroll
                for (int o = 1; o < 16; o <<= 1) p += __shfl_xor(p, o, 64);
                part[m][rr] = p;
            }
        if (l15 == 0)
            #pragma unroll
            for (int m = 0; m < 4; ++m)
                #pragma unroll
                for (int rr = 0; rr < 4; ++rr)
                    red[m * 16 + l4 * 4 + rr][wid] = part[m][rr];
        __syncthreads();
        if (wid == 0 && l15 == 0)
            #pragma unroll
            for (int m = 0; m < 4; ++m)
                #pragma unroll
                for (int rr = 0; rr < 4; ++rr) {
                    int row = m * 16 + l4 * 4 + rr;
                    float4 rv = *(const float4*)&red[row][0];
                    wr[row] = rv.x + rv.y + rv.z + rv.w + b2s;
                }
        __syncthreads();
    }

    // ---- P4: attn2 = softmax(attn * gaussian(wrow)); W = bf16(attn2) ----
    #pragma unroll
    for (int m = 0; m < 4; ++m)
        #pragma unroll
        for (int rr = 0; rr < 4; ++rr) {
            int row = m * 16 + l4 * 4 + rr;
            float wv = wr[row];
            float idn = 1.f / (2.f * wv * wv + 1e-6f);
            int rg = row0 + row;
            #pragma unroll
            for (int n = 0; n < 4; ++n) {
                float d = (float)(wn + n * 16 + l15 - rg);
                sa[m][n][rr] *= __expf(-d * d * idn);
            }
        }
    row_softmax(sa, red, wid, l15, l4);
    #pragma unroll
    for (int m = 0; m < 4; ++m)
        #pragma unroll
        for (int rr = 0; rr < 4; ++rr) {
            int row = m * 16 + l4 * 4 + rr;
            #pragma unroll
            for (int n = 0; n < 4; ++n)
                wrW(W, row, wn + n * 16 + l15, f2bf(sa[m][n][rr]));
        }
    __syncthreads();

    // ---- P5: av = attn2 @ v  (two 256-col halves; sa=av0, acc=av1) ----
    gemm_from_W<true>(sa,  v,         256, 256, W, Bs, tid, lane, wn, l15, l4, slotp);
    gemm_from_W<true>(acc, v + 65536, 256, 256, W, Bs, tid, lane, wn, l15, l4, slotp);

    // ---- P6: out = av @ w_out + b_out, K-split accumulation ----
    // W <- av0 (cols e=0..255); attn2 dead (last gemm barrier covers reads)
    #pragma unroll
    for (int m = 0; m < 4; ++m)
        #pragma unroll
        for (int rr = 0; rr < 4; ++rr) {
            int row = m * 16 + l4 * 4 + rr;
            #pragma unroll
            for (int n = 0; n < 4; ++n)
                wrW(W, row, wn + n * 16 + l15, f2bf(sa[m][n][rr]));
        }
    f32x4 o0[4][4], o1[4][4];
    gemm_from_W<true>(o0, woT,                512, 256, W, Bs, tid, lane, wn, l15, l4, slotp);
    gemm_from_W<true>(o1, woT + 131072,       512, 256, W, Bs, tid, lane, wn, l15, l4, slotp);
    // W <- av1 (cols e=256..511)
    #pragma unroll
    for (int m = 0; m < 4; ++m)
        #pragma unroll
        for (int rr = 0; rr < 4; ++rr) {
            int row = m * 16 + l4 * 4 + rr;
            #pragma unroll
            for (int n = 0; n < 4; ++n)
                wrW(W, row, wn + n * 16 + l15, f2bf(acc[m][n][rr]));
        }
    gemm_from_W<false>(o0, woT + 256,          512, 256, W, Bs, tid, lane, wn, l15, l4, slotp);
    gemm_from_W<false>(o1, woT + 131072 + 256, 512, 256, W, Bs, tid, lane, wn, l15, l4, slotp);

    float bo0[4], bo1[4];
    #pragma unroll
    for (int n = 0; n < 4; ++n) {
        bo0[n] = bov[wn + n * 16 + l15];
        bo1[n] = bov[256 + wn + n * 16 + l15];
    }
    #pragma unroll
    for (int m = 0; m < 4; ++m)
        #pragma unroll
        for (int rr = 0; rr < 4; ++rr) {
            int row = row0 + m * 16 + l4 * 4 + rr;
            size_t ob = ((size_t)z * 256 + row) * 512;
            #pragma unroll
            for (int n = 0; n < 4; ++n) {
                out[ob + wn + n * 16 + l15]       = o0[m][n][rr] + bo0[n];
                out[ob + 256 + wn + n * 16 + l15] = o1[m][n][rr] + bo1[n];
            }
        }
}

// ---------------------------------------------------------------------------
// fp32 [R][C] -> bf16 [C][R] (weights)
__global__ __launch_bounds__(256) void trans_f2b_k(
    const float* __restrict__ in, u16* __restrict__ out, int R, int C)
{
    __shared__ u16 t[64][80];
    const int bx = blockIdx.x, by = blockIdx.y;
    const int tid = threadIdx.x;
    const int r = tid >> 2, c16 = (tid & 3) * 16;
    const float* ip = in + (size_t)(by * 64 + r) * C + bx * 64 + c16;
    #pragma unroll
    for (int j = 0; j < 4; ++j) {
        float4 vv = *(const float4*)(ip + j * 4);
        t[r][c16 + j * 4 + 0] = f2bf(vv.x);
        t[r][c16 + j * 4 + 1] = f2bf(vv.y);
        t[r][c16 + j * 4 + 2] = f2bf(vv.z);
        t[r][c16 + j * 4 + 3] = f2bf(vv.w);
    }
    __syncthreads();
    const int orow = tid >> 2, oc = (tid & 3) * 16;
    u16 o[16];
    #pragma unroll
    for (int j = 0; j < 16; ++j) o[j] = t[oc + j][orow];
    u16* op = out + (size_t)(bx * 64 + orow) * R + by * 64 + oc;
    *(int4*)op       = *(const int4*)&o[0];
    *(int4*)(op + 8) = *(const int4*)&o[8];
}

// bf16 [R][C] -> bf16 [C][R], batched (v -> vT)
__global__ __launch_bounds__(256) void trans_b2b_k(
    const u16* __restrict__ in, u16* __restrict__ out,
    int ldin, int R, long sIn, long sOut)
{
    __shared__ u16 t[64][80];
    const int bx = blockIdx.x, by = blockIdx.y;
    const long zz = blockIdx.z;
    const u16* ip = in + zz * sIn;
    u16* op = out + zz * sOut;
    const int tid = threadIdx.x;
    const int r = tid >> 2, c16 = (tid & 3) * 16;
    const u16* src = ip + (size_t)(by * 64 + r) * ldin + bx * 64 + c16;
    *(int4*)&t[r][c16]     = *(const int4*)src;
    *(int4*)&t[r][c16 + 8] = *(const int4*)(src + 8);
    __syncthreads();
    const int orow = tid >> 2, oc = (tid & 3) * 16;
    u16 o[16];
    #pragma unroll
    for (int j = 0; j < 16; ++j) o[j] = t[oc + j][orow];
    u16* dst = op + (size_t)(bx * 64 + orow) * R + by * 64 + oc;
    *(int4*)dst       = *(const int4*)&o[0];
    *(int4*)(dst + 8) = *(const int4*)&o[8];
}

// fp32 -> bf16 flat convert
__global__ __launch_bounds__(256) void conv_b_k(
    const float* __restrict__ in, u16* __restrict__ out, int n8)
{
    int i = blockIdx.x * 256 + threadIdx.x;
    if (i >= n8) return;
    float4 a = ((const float4*)in)[i * 2], b = ((const float4*)in)[i * 2 + 1];
    u16 o[8] = { f2bf(a.x), f2bf(a.y), f2bf(a.z), f2bf(a.w),
                 f2bf(b.x), f2bf(b.y), f2bf(b.z), f2bf(b.w) };
    ((int4*)out)[i] = *(const int4*)o;
}

// ---------------------------------------------------------------------------
extern "C" void kernel_launch(void* const* d_in, const int* in_sizes, int n_in,
                              void* d_out, int out_size, void* d_ws, size_t ws_size,
                              hipStream_t stream) {
    const float* x     = (const float*)d_in[0];
    const float* w_qkv = (const float*)d_in[1];
    const float* pos   = (const float*)d_in[2];
    const float* w1    = (const float*)d_in[3];
    const float* b1    = (const float*)d_in[4];
    const float* w2    = (const float*)d_in[5];
    const float* b2    = (const float*)d_in[6];
    const float* w_out = (const float*)d_in[7];
    const float* b_out = (const float*)d_in[8];
    float* out = (float*)d_out;
    char* ws = (char*)d_ws;

    u16* xb    = (u16*)(ws);                      // [0,32M)
    u16* vT    = (u16*)(ws);                      // [0,32M) after xb dead
    u16* qkvb  = (u16*)(ws + 33554432);           // [32,128M) q|k|v
    u16* wqkvT = (u16*)(ws + 134217728);
    u16* w1T   = (u16*)(ws + 135790592);
    u16* woT   = (u16*)(ws + 135921664);
    if (ws_size < (size_t)136445952) return;

    u16* qb = qkvb;
    u16* kb = qkvb + 16777216;
    u16* vb = qkvb + 33554432;

    dim3 blk(256);

    conv_b_k<<<dim3(8192), blk, 0, stream>>>(x, xb, 2097152);
    trans_f2b_k<<<dim3(24, 8), blk, 0, stream>>>(w_qkv, wqkvT, 512, 1536);
    trans_f2b_k<<<dim3(4, 4), blk, 0, stream>>>(w1, w1T, 256, 256);
    trans_f2b_k<<<dim3(8, 8), blk, 0, stream>>>(w_out, woT, 512, 512);

    qkv_k<<<dim3(256, 4, 3), blk, 0, stream>>>(xb, wqkvT, qkvb);

    trans_b2b_k<<<dim3(8, 4, 128), blk, 0, stream>>>(vb, vT, 512, 256, 131072L, 131072L);

    fused_k<<<dim3(4, 128), blk, 0, stream>>>(
        qb, kb, vT, w1T, woT, pos, b1, w2, b2, b_out, out);
}